// Round 10
// baseline (347.876 us; speedup 1.0000x reference)
//
#include <hip/hip_runtime.h>

#define D_MODEL 2048
#define T_SEQ   2048
#define NBATCH  2
#define NH      16
#define NG      4
#define HD      128
#define NQKV    3072   // 2048 Q + 512 K + 512 V

typedef short bf16x8 __attribute__((ext_vector_type(8)));
typedef float f32x4  __attribute__((ext_vector_type(4)));
typedef float f32x16 __attribute__((ext_vector_type(16)));
typedef short s16x4  __attribute__((ext_vector_type(4)));
typedef unsigned u32x4 __attribute__((ext_vector_type(4)));

__device__ __forceinline__ short f2bf(float f) {
  union { float f; unsigned u; } v; v.f = f;
  unsigned r = v.u + 0x7fffu + ((v.u >> 16) & 1u);   // RNE
  return (short)(r >> 16);
}

__device__ __forceinline__ float bf2f(short s) {
  union { unsigned u; float f; } v; v.u = ((unsigned)(unsigned short)s) << 16;
  return v.f;
}

__device__ __forceinline__ float fast_exp2(float x) {
#if __has_builtin(__builtin_amdgcn_exp2f)
  return __builtin_amdgcn_exp2f(x);
#else
  return __expf(x * 0.6931471805599453f);
#endif
}

// packed f32x2 -> bf16x2 (RNE), dst.lo = a, dst.hi = b
__device__ __forceinline__ unsigned cvt_pk_bf16(float a, float b) {
  unsigned r;
  asm("v_cvt_pk_bf16_f32 %0, %1, %2" : "=v"(r) : "v"(a), "v"(b));
  return r;
}

// v_permlane32_swap_b32: swaps hi 32 lanes of a with lo 32 lanes of b.
__device__ __forceinline__ void permlane32_swap(unsigned &a, unsigned &b) {
  asm("v_permlane32_swap_b32 %0, %1" : "+v"(a), "+v"(b));
}

__device__ __forceinline__ void gload16(const void* g, void* l) {
  __builtin_amdgcn_global_load_lds(
      (const __attribute__((address_space(1))) void*)g,
      (__attribute__((address_space(3))) void*)l, 16, 0, 0);
}

// ---------------- convert x (fp32 -> bf16) ----------------
__global__ __launch_bounds__(256) void convert_x_kernel(
    const float* __restrict__ x, short* __restrict__ o, int n) {
  int i = (blockIdx.x * 256 + threadIdx.x) * 4;
  if (i >= n) return;
  float4 v = *(const float4*)(x + i);
  s16x4 s;
  s[0] = f2bf(v.x); s[1] = f2bf(v.y); s[2] = f2bf(v.z); s[3] = f2bf(v.w);
  *(s16x4*)(o + i) = s;
}

// ------------- transpose+convert weights: dst[n][k] = W[k][n] -------------
__global__ __launch_bounds__(256) void wtrans_kernel(
    const float* __restrict__ W, short* __restrict__ dst,
    int K, int N, int rowOff, int dstStride) {
  __shared__ float t[32][33];
  int tx = threadIdx.x & 31, ty = threadIdx.x >> 5;   // ty 0..7
  int kb = blockIdx.x * 32, nb = blockIdx.y * 32;
#pragma unroll
  for (int i = 0; i < 4; ++i)
    t[ty + 8*i][tx] = W[(long)(kb + ty + 8*i) * N + nb + tx];
  __syncthreads();
#pragma unroll
  for (int i = 0; i < 4; ++i)
    dst[(long)(rowOff + nb + ty + 8*i) * dstStride + kb + tx] = f2bf(t[tx][ty + 8*i]);
}

// ------------- transpose V slice of QKV -> VT[b][g][d][s] (bf16) -------------
__global__ __launch_bounds__(256) void vtrans_kernel(
    const short* __restrict__ qkv, short* __restrict__ vt) {
  __shared__ short t[32][33];
  int bg = blockIdx.z; int b = bg >> 2, g = bg & 3;
  int sb = blockIdx.x * 32, db = blockIdx.y * 32;
  int tx = threadIdx.x & 31, ty = threadIdx.x >> 5;
  const short* src = qkv + (long)(b * T_SEQ) * NQKV + D_MODEL + NG * HD + g * HD;
#pragma unroll
  for (int i = 0; i < 4; ++i)
    t[ty + 8*i][tx] = src[(long)(sb + ty + 8*i) * NQKV + db + tx];
  __syncthreads();
  short* dst = vt + ((long)bg * HD + db) * T_SEQ + sb;
#pragma unroll
  for (int i = 0; i < 4; ++i)
    dst[(long)(ty + 8*i) * T_SEQ + tx] = t[tx][ty + 8*i];
}

// ------------- 256-tile GEMM, 8 waves, counted-wait pipeline (T3/T4/T5) ----
// Exact R5 version (best measured GEMM config; R8's 128-tile variant was
// ~13us slower total — 64 MFMA/barrier amortization beats 2-block residency).
template <int BN, int MODE>
__global__ __launch_bounds__(512, 2) void gemm256_kernel(
    const short* __restrict__ A, const short* __restrict__ BT,
    const float* __restrict__ b0, const float* __restrict__ b1, const float* __restrict__ b2,
    void* __restrict__ Cout, int M, int N, int K) {
  constexpr int BM = 256, BK = 64;
  constexpr int NFR = BN / 64;              // B frags per wave (4 or 2)
  constexpr int ASZ = BM * BK;              // shorts per A buffer (16384)
  constexpr int BSZ = BN * BK;              // shorts per B buffer
  constexpr int ACH = (ASZ * 2 / 16) / 512; // A chunks per thread (4)
  constexpr int BCH = (BSZ * 2 / 16) / 512; // B chunks per thread (4 or 2)
  __shared__ __align__(16) short smem[(ASZ + BSZ) * 2];

  const int tid = threadIdx.x;
  const int w = tid >> 6, lane = tid & 63;
  const int l15 = lane & 15, quad = lane >> 4;
  const int wr = w & 1, wc = w >> 1;
  const int nb = blockIdx.x, mb = blockIdx.y;
  const short* Ab = A + (long)mb * BM * K;
  const short* Bb = BT + (long)nb * BN * K;

  f32x4 acc[8][NFR];
#pragma unroll
  for (int i = 0; i < 8; ++i)
#pragma unroll
    for (int j = 0; j < NFR; ++j) acc[i][j] = 0.0f;

  int aoff[ACH], boff[BCH];
#pragma unroll
  for (int i = 0; i < ACH; ++i) {
    int chunk = i * 512 + tid;
    int r = chunk >> 3, c = chunk & 7, gc = c ^ (r & 7);
    aoff[i] = r * K + gc * 8;
  }
#pragma unroll
  for (int i = 0; i < BCH; ++i) {
    int chunk = i * 512 + tid;
    int r = chunk >> 3, c = chunk & 7, gc = c ^ (r & 7);
    boff[i] = r * K + gc * 8;
  }

#pragma unroll
  for (int i = 0; i < ACH; ++i) gload16(Ab + aoff[i], smem + (i * 512 + tid) * 8);
#pragma unroll
  for (int i = 0; i < BCH; ++i) gload16(Bb + boff[i], smem + ASZ + (i * 512 + tid) * 8);

  const int NT = K / BK;
  int cur = 0;
  for (int t = 0; t < NT; ++t) {
    asm volatile("s_waitcnt vmcnt(0)" ::: "memory");
    __builtin_amdgcn_s_barrier();
    asm volatile("" ::: "memory");
    if (t + 1 < NT) {
      const int k0n = (t + 1) * BK;
      short* An = smem + (cur ^ 1) * (ASZ + BSZ);
      short* Bn = An + ASZ;
#pragma unroll
      for (int i = 0; i < ACH; ++i) gload16(Ab + k0n + aoff[i], An + (i * 512 + tid) * 8);
#pragma unroll
      for (int i = 0; i < BCH; ++i) gload16(Bb + k0n + boff[i], Bn + (i * 512 + tid) * 8);
    }
    __builtin_amdgcn_sched_barrier(0);
    const short* As = smem + cur * (ASZ + BSZ);
    const short* Bs = As + ASZ;
#pragma unroll
    for (int ks = 0; ks < 2; ++ks) {
      bf16x8 af[8], bfr[NFR];
#pragma unroll
      for (int i = 0; i < 8; ++i) {
        int r = wr * 128 + i * 16 + l15;
        af[i] = *(const bf16x8*)(As + r * 64 + (((ks * 4 + quad) ^ (r & 7)) * 8));
      }
#pragma unroll
      for (int j = 0; j < NFR; ++j) {
        int r = wc * (NFR * 16) + j * 16 + l15;
        bfr[j] = *(const bf16x8*)(Bs + r * 64 + (((ks * 4 + quad) ^ (r & 7)) * 8));
      }
      __builtin_amdgcn_s_setprio(1);
#pragma unroll
      for (int i = 0; i < 8; ++i)
#pragma unroll
        for (int j = 0; j < NFR; ++j)
          acc[i][j] = __builtin_amdgcn_mfma_f32_16x16x32_bf16(af[i], bfr[j], acc[i][j], 0, 0, 0);
      __builtin_amdgcn_s_setprio(0);
    }
    cur ^= 1;
  }

  float biasv[NFR];
#pragma unroll
  for (int j = 0; j < NFR; ++j) {
    int col = nb * BN + wc * (NFR * 16) + j * 16 + l15;
    float bv;
    if (MODE == 0) {
      if (col < 2048)      bv = b0[col];
      else if (col < 2560) bv = b1[col - 2048];
      else                 bv = b2[col - 2560];
    } else bv = b0[col];
    biasv[j] = bv;
  }
  if (MODE == 0) {
    short* C = (short*)Cout;
#pragma unroll
    for (int i = 0; i < 8; ++i)
#pragma unroll
      for (int j = 0; j < NFR; ++j)
#pragma unroll
        for (int r = 0; r < 4; ++r) {
          int row = mb * BM + wr * 128 + i * 16 + quad * 4 + r;
          int col = nb * BN + wc * (NFR * 16) + j * 16 + l15;
          C[(long)row * N + col] = f2bf(acc[i][j][r] + biasv[j]);
        }
  } else {
    float* C = (float*)Cout;
#pragma unroll
    for (int i = 0; i < 8; ++i)
#pragma unroll
      for (int j = 0; j < NFR; ++j)
#pragma unroll
        for (int r = 0; r < 4; ++r) {
          int row = mb * BM + wr * 128 + i * 16 + quad * 4 + r;
          int col = nb * BN + wc * (NFR * 16) + j * 16 + l15;
          C[(long)row * N + col] = acc[i][j][r] + biasv[j];
        }
  }
}

// ---------------- fused attention v13: T15 pipelined tiles -------------------
// (Re-submitted unchanged — R9 bench was an infra failure, hypothesis untested.)
// v9 dataflow (32x32 MFMA, S^T = K·Q^T, lane-local softmax, in-register P via
// cvt_pk + permlane32_swap) restructured as a one-tile software pipeline:
// iteration t computes QK^T(t) WHILE finishing softmax(t-1)+PV(t-1) — the
// serial SM chain hides under QK's MFMAs (MFMA/VALU pipes are independent).
// Two named sacc states (sA/sB) statically indexed via even/odd peeling.
// Staging via global_load_lds + counted wait: issue K(t+1),V(t) at top of
// iter t into the idle dbuf halves; vmcnt(0)+raw s_barrier at the bottom —
// ONE barrier/tile, loads covered by the whole iteration's compute, no reg
// prefetch (frees 32 VGPR for the pipeline state). Occupancy is grid-capped
// (512 blocks / 256 CUs = 2 blocks/CU) so VGPR up to 256 is free.
// Buffer audit (all separated by barriers): iter t reads Ks[t&1], Vs[(t-1)&1];
// writes K(t+1)->Ks[(t+1)&1] (last read iter t-1), V(t)->Vs[t&1] (last read
// iter t-1). vmcnt(0) at end of t drains exactly what iter t+1 reads.
__global__ __launch_bounds__(256, 2) void attn_kernel(
    const short* __restrict__ qkv, const short* __restrict__ vt,
    short* __restrict__ aout) {
  __shared__ __align__(16) short smem[32768];   // 64 KB: Ks0|Ks1|Vs0|Vs1 (16KB each)

  const int tid = threadIdx.x;
  const int w = tid >> 6, lane = tid & 63;
  const int l31 = lane & 31, hi = lane >> 5;
  const int qt = blockIdx.x, h = blockIdx.y, b = blockIdx.z;
  const int g = h >> 2;
  const short* qbase = qkv + (long)(b * T_SEQ + qt * 128) * NQKV + h * HD;
  const short* kbase = qkv + (long)(b * T_SEQ) * NQKV + D_MODEL + g * HD;
  const short* vbase = vt + (long)(b * NG + g) * HD * T_SEQ;
  const float QSCALE = 0.08838834764831845f * 1.4426950408889634f;  // 1/sqrt(128)*log2(e)
  const int NT = T_SEQ / 64;   // 32

  int kroff[4], vroff[4], dst[4];
#pragma unroll
  for (int t = 0; t < 4; ++t) {
    int chunk = w * 256 + t * 64 + lane;
    { int r = chunk >> 4, c = chunk & 15, gc = c ^ (r & 15);
      kroff[t] = r * NQKV + gc * 8; }
    { int r = chunk >> 3, c = chunk & 7, gc = c ^ (r & 7);
      vroff[t] = r * T_SEQ + gc * 8; }
    dst[t] = chunk * 8;
  }

  bf16x8 qfrag[8];
  {
    const short* qrow = qbase + (long)(w * 32 + l31) * NQKV + hi * 8;
#pragma unroll
    for (int ks = 0; ks < 8; ++ks) {
      bf16x8 v = *(const bf16x8*)(qrow + ks * 16);
#pragma unroll
      for (int e = 0; e < 8; ++e) v[e] = f2bf(bf2f(v[e]) * QSCALE);
      qfrag[ks] = v;
    }
  }

  f32x16 oaccT[4];
#pragma unroll
  for (int i = 0; i < 4; ++i) oaccT[i] = 0.0f;
  float lpart[4] = {0.f, 0.f, 0.f, 0.f};
  f32x16 sA[2][2], sB[2][2];

  auto issueK = [&](int t) {
    const short* kb2 = kbase + (long)t * 64 * NQKV;
    short* Kd = smem + (t & 1) * 8192;
#pragma unroll
    for (int tt = 0; tt < 4; ++tt) gload16(kb2 + kroff[tt], Kd + dst[tt]);
  };
  auto issueV = [&](int t) {
    const short* vb2 = vbase + t * 64;
    short* Vd = smem + 16384 + (t & 1) * 8192;
#pragma unroll
    for (int tt = 0; tt < 4; ++tt) gload16(vb2 + vroff[tt], Vd + dst[tt]);
  };
  auto qk = [&](int t, f32x16 (&S)[2][2]) {
    const short* KS = smem + (t & 1) * 8192;
    S[0][0] = 0.0f; S[0][1] = 0.0f; S[1][0] = 0.0f; S[1][1] = 0.0f;
#pragma unroll
    for (int ks = 0; ks < 8; ++ks)
#pragma unroll
      for (int sb = 0; sb < 2; ++sb) {
        int srow = sb * 32 + l31;
        bf16x8 a = *(const bf16x8*)(KS + srow * 128 + (((ks * 2 + hi) ^ (srow & 15)) * 8));
        S[sb][ks & 1] = __builtin_amdgcn_mfma_f32_32x32x16_bf16(a, qfrag[ks], S[sb][ks & 1], 0, 0, 0);
      }
  };
  auto fin = [&](int tv, f32x16 (&S)[2][2]) {
    const short* VS = smem + 16384 + (tv & 1) * 8192;
    float p0[16], p1[16];
#pragma unroll
    for (int r = 0; r < 16; ++r) p0[r] = fast_exp2(S[0][0][r] + S[0][1][r]);
#pragma unroll
    for (int r = 0; r < 16; ++r) p1[r] = fast_exp2(S[1][0][r] + S[1][1][r]);
#pragma unroll
    for (int r = 0; r < 16; ++r) lpart[r & 3] += p0[r] + p1[r];
#pragma unroll
    for (int k2 = 0; k2 < 4; ++k2) {
      const float* pp = (k2 & 2) ? p1 : p0;
      const int bo = (k2 & 1) * 8;
      unsigned Pa = cvt_pk_bf16(pp[bo + 0], pp[bo + 1]);
      unsigned Pb = cvt_pk_bf16(pp[bo + 2], pp[bo + 3]);
      unsigned Pc = cvt_pk_bf16(pp[bo + 4], pp[bo + 5]);
      unsigned Pd = cvt_pk_bf16(pp[bo + 6], pp[bo + 7]);
      permlane32_swap(Pa, Pc);
      permlane32_swap(Pb, Pd);
      u32x4 pu; pu[0] = Pa; pu[1] = Pb; pu[2] = Pc; pu[3] = Pd;
      bf16x8 pfr = __builtin_bit_cast(bf16x8, pu);
#pragma unroll
      for (int db = 0; db < 4; ++db) {
        int drow = db * 32 + l31;
        bf16x8 a = *(const bf16x8*)(VS + drow * 64 + (((k2 * 2 + hi) ^ (drow & 7)) * 8));
        oaccT[db] = __builtin_amdgcn_mfma_f32_32x32x16_bf16(a, pfr, oaccT[db], 0, 0, 0);
      }
    }
  };

  // ---- prologue: K(0) resident, then pipeline-fill iteration t=0 ----
  issueK(0);
  asm volatile("s_waitcnt vmcnt(0)" ::: "memory");
  __builtin_amdgcn_s_barrier();
  issueK(1); issueV(0);
  qk(0, sA);
  asm volatile("s_waitcnt vmcnt(0)" ::: "memory");
  __builtin_amdgcn_s_barrier();

  // ---- main loop: pairs (odd t, even t+1), t = 1..30 ----
  for (int t = 1; t < NT - 1; t += 2) {
    issueK(t + 1); issueV(t);
    qk(t, sB);
    fin(t - 1, sA);
    asm volatile("s_waitcnt vmcnt(0)" ::: "memory");
    __builtin_amdgcn_s_barrier();

    issueK(t + 2); issueV(t + 1);
    qk(t + 1, sA);
    fin(t, sB);
    asm volatile("s_waitcnt vmcnt(0)" ::: "memory");
    __builtin_amdgcn_s_barrier();
  }

  // ---- peeled t = NT-1 = 31 (odd): no K(32) ----
  issueV(NT - 1);
  qk(NT - 1, sB);
  fin(NT - 2, sA);
  asm volatile("s_waitcnt vmcnt(0)" ::: "memory");
  __builtin_amdgcn_s_barrier();
  fin(NT - 1, sB);

  // ---- epilogue ----
  float lsum = (lpart[0] + lpart[1]) + (lpart[2] + lpart[3]);
  float lfull = lsum + __shfl_xor(lsum, 32);
  float inv = 1.0f / lfull;

  __syncthreads();   // all waves done with Vs reads before Osm overwrite is read back
  short* Osm = smem;   // 128 x 128 bf16 (Ks0+Ks1 region), 8-short-chunk XOR swizzle
  const int qrl = w * 32 + l31;
#pragma unroll
  for (int db = 0; db < 4; ++db)
#pragma unroll
    for (int r = 0; r < 16; ++r) {
      int dloc = (r & 3) + 8 * (r >> 2) + 4 * hi;
      int d = db * 32 + dloc;
      int c = d >> 3;
      Osm[qrl * 128 + ((c ^ (qrl & 15)) * 8) + (d & 7)] = f2bf(oaccT[db][r] * inv);
    }
  __syncthreads();

  short* obase = aout + (long)(b * T_SEQ + qt * 128) * D_MODEL + h * HD;
  const int row = tid >> 1, ch = tid & 1;
#pragma unroll
  for (int j = 0; j < 8; ++j) {
    int c2 = ch * 8 + j;
    bf16x8 v = *(const bf16x8*)(Osm + row * 128 + ((c2 ^ (row & 15)) * 8));
    *(bf16x8*)(obase + (long)row * D_MODEL + c2 * 8) = v;
  }
}

// ---------------- launcher ----------------
extern "C" void kernel_launch(void* const* d_in, const int* in_sizes, int n_in,
                              void* d_out, int out_size, void* d_ws, size_t ws_size,
                              hipStream_t stream) {
  const float* x  = (const float*)d_in[0];
  const float* Wq = (const float*)d_in[1];
  const float* bq = (const float*)d_in[2];
  const float* Wk = (const float*)d_in[3];
  const float* bk = (const float*)d_in[4];
  const float* Wv = (const float*)d_in[5];
  const float* bv = (const float*)d_in[6];
  const float* Wo = (const float*)d_in[7];
  const float* bo = (const float*)d_in[8];

  const long NTOK = (long)NBATCH * T_SEQ;          // 4096
  short* xb    = (short*)d_ws;                     // [4096][2048]
  short* wqkvT = xb + NTOK * D_MODEL;              // [3072][2048]
  short* woT   = wqkvT + (long)NQKV * D_MODEL;     // [2048][2048]
  short* qkvb  = woT + (long)D_MODEL * D_MODEL;    // [4096][3072]
  short* vtb   = qkvb + NTOK * NQKV;               // [2][4][128][2048]
  short* attnb = vtb + (long)NBATCH * NG * HD * T_SEQ;  // [4096][2048]

  int nX = (int)(NTOK * D_MODEL);
  convert_x_kernel<<<nX / (256 * 4), 256, 0, stream>>>(x, xb, nX);
  wtrans_kernel<<<dim3(D_MODEL / 32, D_MODEL / 32), 256, 0, stream>>>(Wq, wqkvT, D_MODEL, D_MODEL, 0, D_MODEL);
  wtrans_kernel<<<dim3(D_MODEL / 32, 512 / 32), 256, 0, stream>>>(Wk, wqkvT, D_MODEL, 512, 2048, D_MODEL);
  wtrans_kernel<<<dim3(D_MODEL / 32, 512 / 32), 256, 0, stream>>>(Wv, wqkvT, D_MODEL, 512, 2560, D_MODEL);
  wtrans_kernel<<<dim3(D_MODEL / 32, D_MODEL / 32), 256, 0, stream>>>(Wo, woT, D_MODEL, D_MODEL, 0, D_MODEL);

  gemm256_kernel<256, 0><<<dim3(NQKV / 256, NTOK / 256), 512, 0, stream>>>(
      xb, wqkvT, bq, bk, bv, (void*)qkvb, (int)NTOK, NQKV, D_MODEL);

  vtrans_kernel<<<dim3(T_SEQ / 32, HD / 32, NBATCH * NG), 256, 0, stream>>>(qkvb, vtb);

  attn_kernel<<<dim3(T_SEQ / 128, NH, NBATCH), 256, 0, stream>>>(qkvb, vtb, attnb);

  gemm256_kernel<128, 1><<<dim3(D_MODEL / 128, NTOK / 256), 512, 0, stream>>>(
      attnb, woT, bo, bo, bo, (void*)d_out, (int)NTOK, D_MODEL, D_MODEL);
}

// Round 11
// 297.073 us; speedup vs baseline: 1.1710x; 1.1710x over previous
//
#include <hip/hip_runtime.h>

#define D_MODEL 2048
#define T_SEQ   2048
#define NBATCH  2
#define NH      16
#define NG      4
#define HD      128
#define NQKV    3072   // 2048 Q + 512 K + 512 V

typedef short bf16x8 __attribute__((ext_vector_type(8)));
typedef float f32x4  __attribute__((ext_vector_type(4)));
typedef float f32x16 __attribute__((ext_vector_type(16)));
typedef short s16x4  __attribute__((ext_vector_type(4)));
typedef unsigned u32x2 __attribute__((ext_vector_type(2)));
typedef unsigned u32x4 __attribute__((ext_vector_type(4)));

__device__ __forceinline__ short f2bf(float f) {
  union { float f; unsigned u; } v; v.f = f;
  unsigned r = v.u + 0x7fffu + ((v.u >> 16) & 1u);   // RNE
  return (short)(r >> 16);
}

__device__ __forceinline__ float bf2f(short s) {
  union { unsigned u; float f; } v; v.u = ((unsigned)(unsigned short)s) << 16;
  return v.f;
}

__device__ __forceinline__ float fast_exp2(float x) {
#if __has_builtin(__builtin_amdgcn_exp2f)
  return __builtin_amdgcn_exp2f(x);
#else
  return __expf(x * 0.6931471805599453f);
#endif
}

// packed f32x2 -> bf16x2 (RNE), dst.lo = a, dst.hi = b
__device__ __forceinline__ unsigned cvt_pk_bf16(float a, float b) {
  unsigned r;
  asm("v_cvt_pk_bf16_f32 %0, %1, %2" : "=v"(r) : "v"(a), "v"(b));
  return r;
}

// v_permlane32_swap_b32: swaps hi 32 lanes of a with lo 32 lanes of b.
__device__ __forceinline__ void permlane32_swap(unsigned &a, unsigned &b) {
  asm("v_permlane32_swap_b32 %0, %1" : "+v"(a), "+v"(b));
}

__device__ __forceinline__ void gload16(const void* g, void* l) {
  __builtin_amdgcn_global_load_lds(
      (const __attribute__((address_space(1))) void*)g,
      (__attribute__((address_space(3))) void*)l, 16, 0, 0);
}

// ---------------- convert x (fp32 -> bf16) ----------------
__global__ __launch_bounds__(256) void convert_x_kernel(
    const float* __restrict__ x, short* __restrict__ o, int n) {
  int i = (blockIdx.x * 256 + threadIdx.x) * 4;
  if (i >= n) return;
  float4 v = *(const float4*)(x + i);
  s16x4 s;
  s[0] = f2bf(v.x); s[1] = f2bf(v.y); s[2] = f2bf(v.z); s[3] = f2bf(v.w);
  *(s16x4*)(o + i) = s;
}

// ------------- transpose+convert weights: dst[n][k] = W[k][n] -------------
__global__ __launch_bounds__(256) void wtrans_kernel(
    const float* __restrict__ W, short* __restrict__ dst,
    int K, int N, int rowOff, int dstStride) {
  __shared__ float t[32][33];
  int tx = threadIdx.x & 31, ty = threadIdx.x >> 5;   // ty 0..7
  int kb = blockIdx.x * 32, nb = blockIdx.y * 32;
#pragma unroll
  for (int i = 0; i < 4; ++i)
    t[ty + 8*i][tx] = W[(long)(kb + ty + 8*i) * N + nb + tx];
  __syncthreads();
#pragma unroll
  for (int i = 0; i < 4; ++i)
    dst[(long)(rowOff + nb + ty + 8*i) * dstStride + kb + tx] = f2bf(t[tx][ty + 8*i]);
}

// ------------- transpose V slice of QKV -> VT[b][g][d][s] (bf16) -------------
__global__ __launch_bounds__(256) void vtrans_kernel(
    const short* __restrict__ qkv, short* __restrict__ vt) {
  __shared__ short t[32][33];
  int bg = blockIdx.z; int b = bg >> 2, g = bg & 3;
  int sb = blockIdx.x * 32, db = blockIdx.y * 32;
  int tx = threadIdx.x & 31, ty = threadIdx.x >> 5;
  const short* src = qkv + (long)(b * T_SEQ) * NQKV + D_MODEL + NG * HD + g * HD;
#pragma unroll
  for (int i = 0; i < 4; ++i)
    t[ty + 8*i][tx] = src[(long)(sb + ty + 8*i) * NQKV + db + tx];
  __syncthreads();
  short* dst = vt + ((long)bg * HD + db) * T_SEQ + sb;
#pragma unroll
  for (int i = 0; i < 4; ++i)
    dst[(long)(ty + 8*i) * T_SEQ + tx] = t[tx][ty + 8*i];
}

// ------------- 256-tile GEMM, 8 waves, counted-wait pipeline (T3/T4/T5) ----
// Exact R5 version (best measured GEMM config).
template <int BN, int MODE>
__global__ __launch_bounds__(512, 2) void gemm256_kernel(
    const short* __restrict__ A, const short* __restrict__ BT,
    const float* __restrict__ b0, const float* __restrict__ b1, const float* __restrict__ b2,
    void* __restrict__ Cout, int M, int N, int K) {
  constexpr int BM = 256, BK = 64;
  constexpr int NFR = BN / 64;              // B frags per wave (4 or 2)
  constexpr int ASZ = BM * BK;              // shorts per A buffer (16384)
  constexpr int BSZ = BN * BK;              // shorts per B buffer
  constexpr int ACH = (ASZ * 2 / 16) / 512; // A chunks per thread (4)
  constexpr int BCH = (BSZ * 2 / 16) / 512; // B chunks per thread (4 or 2)
  __shared__ __align__(16) short smem[(ASZ + BSZ) * 2];

  const int tid = threadIdx.x;
  const int w = tid >> 6, lane = tid & 63;
  const int l15 = lane & 15, quad = lane >> 4;
  const int wr = w & 1, wc = w >> 1;
  const int nb = blockIdx.x, mb = blockIdx.y;
  const short* Ab = A + (long)mb * BM * K;
  const short* Bb = BT + (long)nb * BN * K;

  f32x4 acc[8][NFR];
#pragma unroll
  for (int i = 0; i < 8; ++i)
#pragma unroll
    for (int j = 0; j < NFR; ++j) acc[i][j] = 0.0f;

  int aoff[ACH], boff[BCH];
#pragma unroll
  for (int i = 0; i < ACH; ++i) {
    int chunk = i * 512 + tid;
    int r = chunk >> 3, c = chunk & 7, gc = c ^ (r & 7);
    aoff[i] = r * K + gc * 8;
  }
#pragma unroll
  for (int i = 0; i < BCH; ++i) {
    int chunk = i * 512 + tid;
    int r = chunk >> 3, c = chunk & 7, gc = c ^ (r & 7);
    boff[i] = r * K + gc * 8;
  }

#pragma unroll
  for (int i = 0; i < ACH; ++i) gload16(Ab + aoff[i], smem + (i * 512 + tid) * 8);
#pragma unroll
  for (int i = 0; i < BCH; ++i) gload16(Bb + boff[i], smem + ASZ + (i * 512 + tid) * 8);

  const int NT = K / BK;
  int cur = 0;
  for (int t = 0; t < NT; ++t) {
    asm volatile("s_waitcnt vmcnt(0)" ::: "memory");
    __builtin_amdgcn_s_barrier();
    asm volatile("" ::: "memory");
    if (t + 1 < NT) {
      const int k0n = (t + 1) * BK;
      short* An = smem + (cur ^ 1) * (ASZ + BSZ);
      short* Bn = An + ASZ;
#pragma unroll
      for (int i = 0; i < ACH; ++i) gload16(Ab + k0n + aoff[i], An + (i * 512 + tid) * 8);
#pragma unroll
      for (int i = 0; i < BCH; ++i) gload16(Bb + k0n + boff[i], Bn + (i * 512 + tid) * 8);
    }
    __builtin_amdgcn_sched_barrier(0);
    const short* As = smem + cur * (ASZ + BSZ);
    const short* Bs = As + ASZ;
#pragma unroll
    for (int ks = 0; ks < 2; ++ks) {
      bf16x8 af[8], bfr[NFR];
#pragma unroll
      for (int i = 0; i < 8; ++i) {
        int r = wr * 128 + i * 16 + l15;
        af[i] = *(const bf16x8*)(As + r * 64 + (((ks * 4 + quad) ^ (r & 7)) * 8));
      }
#pragma unroll
      for (int j = 0; j < NFR; ++j) {
        int r = wc * (NFR * 16) + j * 16 + l15;
        bfr[j] = *(const bf16x8*)(Bs + r * 64 + (((ks * 4 + quad) ^ (r & 7)) * 8));
      }
      __builtin_amdgcn_s_setprio(1);
#pragma unroll
      for (int i = 0; i < 8; ++i)
#pragma unroll
        for (int j = 0; j < NFR; ++j)
          acc[i][j] = __builtin_amdgcn_mfma_f32_16x16x32_bf16(af[i], bfr[j], acc[i][j], 0, 0, 0);
      __builtin_amdgcn_s_setprio(0);
    }
    cur ^= 1;
  }

  float biasv[NFR];
#pragma unroll
  for (int j = 0; j < NFR; ++j) {
    int col = nb * BN + wc * (NFR * 16) + j * 16 + l15;
    float bv;
    if (MODE == 0) {
      if (col < 2048)      bv = b0[col];
      else if (col < 2560) bv = b1[col - 2048];
      else                 bv = b2[col - 2560];
    } else bv = b0[col];
    biasv[j] = bv;
  }
  if (MODE == 0) {
    short* C = (short*)Cout;
#pragma unroll
    for (int i = 0; i < 8; ++i)
#pragma unroll
      for (int j = 0; j < NFR; ++j)
#pragma unroll
        for (int r = 0; r < 4; ++r) {
          int row = mb * BM + wr * 128 + i * 16 + quad * 4 + r;
          int col = nb * BN + wc * (NFR * 16) + j * 16 + l15;
          C[(long)row * N + col] = f2bf(acc[i][j][r] + biasv[j]);
        }
  } else {
    float* C = (float*)Cout;
#pragma unroll
    for (int i = 0; i < 8; ++i)
#pragma unroll
      for (int j = 0; j < NFR; ++j)
#pragma unroll
        for (int r = 0; r < 4; ++r) {
          int row = mb * BM + wr * 128 + i * 16 + quad * 4 + r;
          int col = nb * BN + wc * (NFR * 16) + j * 16 + l15;
          C[(long)row * N + col] = acc[i][j][r] + biasv[j];
        }
  }
}

// ---------------- fused attention v14: v9 + b64-packed O epilogue ----------
// v9 dataflow (best measured: ~83 us): 32x32 MFMA, S^T = K·Q^T, lane-local
// softmax, in-register P via cvt_pk + permlane32_swap, 4-chain QK^T, dbuf
// LDS one barrier/tile, T14 reg prefetch. CHANGE: epilogue O-transpose now
// writes 16 ds_write_b64 (cvt_pk pairs) instead of 64 scalar ds_write_u16 —
// bank math showed the scalar u16 stores were ~8 lanes/bank (the 4.3M
// SQ_LDS_BANK_CONFLICT), b64 quads are 2 lanes/bank (free). Derivation:
// r=4g+j -> dloc=j+8g+4hi -> quad (db,g) contiguous in chunk c=db*4+g at
// byte 8*hi. Same RNE rounding (v_cvt_pk_bf16_f32), readback unchanged.
__global__ __launch_bounds__(256, 2) void attn_kernel(
    const short* __restrict__ qkv, const short* __restrict__ vt,
    short* __restrict__ aout) {
  __shared__ __align__(16) short smem[32768];   // 64 KB: 2 x (Ks 64x128 | Vs 128x64)

  const int tid = threadIdx.x;
  const int w = tid >> 6, lane = tid & 63;
  const int l31 = lane & 31, hi = lane >> 5;
  const int qt = blockIdx.x, h = blockIdx.y, b = blockIdx.z;
  const int g = h >> 2;
  const short* qbase = qkv + (long)(b * T_SEQ + qt * 128) * NQKV + h * HD;
  const short* kbase = qkv + (long)(b * T_SEQ) * NQKV + D_MODEL + g * HD;
  const short* vbase = vt + (long)(b * NG + g) * HD * T_SEQ;
  const float QSCALE = 0.08838834764831845f * 1.4426950408889634f;  // 1/sqrt(128)*log2(e)

  int kroff[4], vroff[4], dst[4];
#pragma unroll
  for (int t = 0; t < 4; ++t) {
    int chunk = w * 256 + t * 64 + lane;
    { int r = chunk >> 4, c = chunk & 15, gc = c ^ (r & 15);
      kroff[t] = r * NQKV + gc * 8; }
    { int r = chunk >> 3, c = chunk & 7, gc = c ^ (r & 7);
      vroff[t] = r * T_SEQ + gc * 8; }
    dst[t] = chunk * 8;
  }

  bf16x8 qfrag[8];
  {
    const short* qrow = qbase + (long)(w * 32 + l31) * NQKV + hi * 8;
#pragma unroll
    for (int ks = 0; ks < 8; ++ks) {
      bf16x8 v = *(const bf16x8*)(qrow + ks * 16);
#pragma unroll
      for (int e = 0; e < 8; ++e) v[e] = f2bf(bf2f(v[e]) * QSCALE);
      qfrag[ks] = v;
    }
  }

#pragma unroll
  for (int t = 0; t < 4; ++t) {
    gload16(kbase + kroff[t], smem + dst[t]);
    gload16(vbase + vroff[t], smem + 8192 + dst[t]);
  }

  f32x16 oaccT[4];
#pragma unroll
  for (int i = 0; i < 4; ++i) oaccT[i] = 0.0f;
  float lpart[4] = {0.f, 0.f, 0.f, 0.f};

  __syncthreads();   // tile 0 resident

  int cur = 0;
  bf16x8 kpre[4], vpre[4];
  for (int st = 0; st < T_SEQ / 64; ++st) {
    const bool pf = (st + 1 < T_SEQ / 64);
    short* Ks = smem + cur * 16384;
    short* Vs = Ks + 8192;
    if (pf) {   // T14: next tile global->reg, latency hidden under compute
      const short* kb2 = kbase + (long)(st + 1) * 64 * NQKV;
      const short* vb2 = vbase + (st + 1) * 64;
#pragma unroll
      for (int t = 0; t < 4; ++t) {
        kpre[t] = *(const bf16x8*)(kb2 + kroff[t]);
        vpre[t] = *(const bf16x8*)(vb2 + vroff[t]);
      }
    }

    // ---- S^T[s][q] = K·Q^T, 4 independent accumulator chains ----
    f32x16 sacc[2][2];
    sacc[0][0] = 0.0f; sacc[0][1] = 0.0f; sacc[1][0] = 0.0f; sacc[1][1] = 0.0f;
    __builtin_amdgcn_s_setprio(1);
#pragma unroll
    for (int ks = 0; ks < 8; ++ks) {
#pragma unroll
      for (int sb = 0; sb < 2; ++sb) {
        int srow = sb * 32 + l31;
        bf16x8 a = *(const bf16x8*)(Ks + srow * 128 + (((ks * 2 + hi) ^ (srow & 15)) * 8));
        sacc[sb][ks & 1] = __builtin_amdgcn_mfma_f32_32x32x16_bf16(a, qfrag[ks], sacc[sb][ks & 1], 0, 0, 0);
      }
    }
    __builtin_amdgcn_s_setprio(0);

    // ---- softmax: p = 2^(S'), lane-local q-column sums ----
    float p0[16], p1[16];
#pragma unroll
    for (int r = 0; r < 16; ++r) p0[r] = fast_exp2(sacc[0][0][r] + sacc[0][1][r]);
#pragma unroll
    for (int r = 0; r < 16; ++r) p1[r] = fast_exp2(sacc[1][0][r] + sacc[1][1][r]);
#pragma unroll
    for (int r = 0; r < 16; ++r) lpart[r & 3] += p0[r] + p1[r];

    // ---- PV: O^T[d][q] += V^T · P^T ; B-frags via cvt_pk + permlane swap ----
    __builtin_amdgcn_s_setprio(1);
#pragma unroll
    for (int k2 = 0; k2 < 4; ++k2) {
      const float* pp = (k2 & 2) ? p1 : p0;
      const int bo = (k2 & 1) * 8;
      unsigned Pa = cvt_pk_bf16(pp[bo + 0], pp[bo + 1]);
      unsigned Pb = cvt_pk_bf16(pp[bo + 2], pp[bo + 3]);
      unsigned Pc = cvt_pk_bf16(pp[bo + 4], pp[bo + 5]);
      unsigned Pd = cvt_pk_bf16(pp[bo + 6], pp[bo + 7]);
      permlane32_swap(Pa, Pc);
      permlane32_swap(Pb, Pd);
      u32x4 pu; pu[0] = Pa; pu[1] = Pb; pu[2] = Pc; pu[3] = Pd;
      bf16x8 pfr = __builtin_bit_cast(bf16x8, pu);
#pragma unroll
      for (int db = 0; db < 4; ++db) {
        int drow = db * 32 + l31;
        bf16x8 a = *(const bf16x8*)(Vs + drow * 64 + (((k2 * 2 + hi) ^ (drow & 7)) * 8));
        oaccT[db] = __builtin_amdgcn_mfma_f32_32x32x16_bf16(a, pfr, oaccT[db], 0, 0, 0);
      }
    }
    __builtin_amdgcn_s_setprio(0);

    if (pf) {
      short* Kn = smem + (cur ^ 1) * 16384;
      short* Vn = Kn + 8192;
#pragma unroll
      for (int t = 0; t < 4; ++t) {
        *(bf16x8*)(Kn + dst[t]) = kpre[t];
        *(bf16x8*)(Vn + dst[t]) = vpre[t];
      }
    }
    __syncthreads();   // one barrier per tile
    cur ^= 1;
  }

  // ---- epilogue: normalize, b64-packed transpose through LDS ----
  float lsum = (lpart[0] + lpart[1]) + (lpart[2] + lpart[3]);
  float lfull = lsum + __shfl_xor(lsum, 32);
  float inv = 1.0f / lfull;

  short* Osm = smem;   // 128 x 128 bf16, 8-short-chunk XOR swizzle
  const int qrl = w * 32 + l31;
  const int swzbase = qrl * 128;
#pragma unroll
  for (int db = 0; db < 4; ++db)
#pragma unroll
    for (int gq = 0; gq < 4; ++gq) {
      // quad r = 4*gq .. 4*gq+3 -> dloc = (0..3) + 8*gq + 4*hi, chunk c = db*4+gq
      unsigned w0 = cvt_pk_bf16(oaccT[db][4 * gq + 0] * inv, oaccT[db][4 * gq + 1] * inv);
      unsigned w1 = cvt_pk_bf16(oaccT[db][4 * gq + 2] * inv, oaccT[db][4 * gq + 3] * inv);
      int c = db * 4 + gq;
      u32x2 wp; wp[0] = w0; wp[1] = w1;
      *(u32x2*)(Osm + swzbase + ((c ^ (qrl & 15)) * 8) + 4 * hi) = wp;
    }
  __syncthreads();

  short* obase = aout + (long)(b * T_SEQ + qt * 128) * D_MODEL + h * HD;
  const int row = tid >> 1, ch = tid & 1;
#pragma unroll
  for (int j = 0; j < 8; ++j) {
    int c2 = ch * 8 + j;
    bf16x8 v = *(const bf16x8*)(Osm + row * 128 + ((c2 ^ (row & 15)) * 8));
    *(bf16x8*)(obase + (long)row * D_MODEL + c2 * 8) = v;
  }
}

// ---------------- launcher ----------------
extern "C" void kernel_launch(void* const* d_in, const int* in_sizes, int n_in,
                              void* d_out, int out_size, void* d_ws, size_t ws_size,
                              hipStream_t stream) {
  const float* x  = (const float*)d_in[0];
  const float* Wq = (const float*)d_in[1];
  const float* bq = (const float*)d_in[2];
  const float* Wk = (const float*)d_in[3];
  const float* bk = (const float*)d_in[4];
  const float* Wv = (const float*)d_in[5];
  const float* bv = (const float*)d_in[6];
  const float* Wo = (const float*)d_in[7];
  const float* bo = (const float*)d_in[8];

  const long NTOK = (long)NBATCH * T_SEQ;          // 4096
  short* xb    = (short*)d_ws;                     // [4096][2048]
  short* wqkvT = xb + NTOK * D_MODEL;              // [3072][2048]
  short* woT   = wqkvT + (long)NQKV * D_MODEL;     // [2048][2048]
  short* qkvb  = woT + (long)D_MODEL * D_MODEL;    // [4096][3072]
  short* vtb   = qkvb + NTOK * NQKV;               // [2][4][128][2048]
  short* attnb = vtb + (long)NBATCH * NG * HD * T_SEQ;  // [4096][2048]

  int nX = (int)(NTOK * D_MODEL);
  convert_x_kernel<<<nX / (256 * 4), 256, 0, stream>>>(x, xb, nX);
  wtrans_kernel<<<dim3(D_MODEL / 32, D_MODEL / 32), 256, 0, stream>>>(Wq, wqkvT, D_MODEL, D_MODEL, 0, D_MODEL);
  wtrans_kernel<<<dim3(D_MODEL / 32, 512 / 32), 256, 0, stream>>>(Wk, wqkvT, D_MODEL, 512, 2048, D_MODEL);
  wtrans_kernel<<<dim3(D_MODEL / 32, 512 / 32), 256, 0, stream>>>(Wv, wqkvT, D_MODEL, 512, 2560, D_MODEL);
  wtrans_kernel<<<dim3(D_MODEL / 32, D_MODEL / 32), 256, 0, stream>>>(Wo, woT, D_MODEL, D_MODEL, 0, D_MODEL);

  gemm256_kernel<256, 0><<<dim3(NQKV / 256, NTOK / 256), 512, 0, stream>>>(
      xb, wqkvT, bq, bk, bv, (void*)qkvb, (int)NTOK, NQKV, D_MODEL);

  vtrans_kernel<<<dim3(T_SEQ / 32, HD / 32, NBATCH * NG), 256, 0, stream>>>(qkvb, vtb);

  attn_kernel<<<dim3(T_SEQ / 128, NH, NBATCH), 256, 0, stream>>>(qkvb, vtb, attnb);

  gemm256_kernel<128, 1><<<dim3(D_MODEL / 128, NTOK / 256), 512, 0, stream>>>(
      attnb, woT, bo, bo, bo, (void*)d_out, (int)NTOK, D_MODEL, D_MODEL);
}